// Round 1
// baseline (742.784 us; speedup 1.0000x reference)
//
#include <hip/hip_runtime.h>
#include <stdint.h>

typedef __bf16 bf16;
typedef bf16 bf16x8 __attribute__((ext_vector_type(8)));
typedef bf16 bf16x4 __attribute__((ext_vector_type(4)));
typedef float f32x4 __attribute__((ext_vector_type(4)));

#define B_   16
#define CI   192
#define CO   192
#define H_   128
#define W_   128
#define KE   8
#define LD   64
#define KTOT 1728   // 9*192
#define HP   130    // padded H/W
#define NPX  (H_*W_)

__device__ __forceinline__ void gll16(const void* g, void* l) {
  __builtin_amdgcn_global_load_lds(
      (const __attribute__((address_space(1))) unsigned int*)g,
      (__attribute__((address_space(3))) unsigned int*)l, 16, 0, 0);
}

__device__ __forceinline__ float silu_f(float x) {
  return x / (1.f + __expf(-x));
}

// ---------------- attention softmax: latent[16,64] -> attn[16,8] ----------------
__global__ void k_attn(const float* __restrict__ latent, const float* __restrict__ attn_w,
                       const float* __restrict__ attn_b, float* __restrict__ attn) {
  int t = threadIdx.x;           // 128 threads: b = t>>3, k = t&7
  int b = t >> 3, k = t & 7;
  float s = attn_b[k];
  for (int d = 0; d < LD; ++d) s += latent[b*LD + d] * attn_w[k*LD + d];
  float m = s;
  for (int off = 4; off; off >>= 1) m = fmaxf(m, __shfl_xor(m, off, 8));
  float e = __expf(s - m);
  float sum = e;
  for (int off = 4; off; off >>= 1) sum += __shfl_xor(sum, off, 8);
  attn[t] = e / sum;
}

// ---------------- dynamic bias: bdyn[b][o] = sum_k attn[b][k]*expert_b[k][o] ----------------
__global__ void k_bdyn(const float* __restrict__ attn, const float* __restrict__ expert_b,
                       float* __restrict__ bdyn) {
  int j = blockIdx.x * 256 + threadIdx.x;
  if (j >= B_ * CO) return;
  int b = j / CO, o = j - b * CO;
  float s = 0.f;
  #pragma unroll
  for (int e = 0; e < KE; ++e) s += attn[b*KE + e] * expert_b[e*CO + o];
  bdyn[j] = s;
}

// ---------------- dynamic weights, reordered [b][o][rs][i] bf16 ----------------
__global__ void k_wdyn(const float* __restrict__ expert_w, const float* __restrict__ attn,
                       bf16* __restrict__ w_re) {
  int o = blockIdx.x >> 4, b = blockIdx.x & 15;
  __shared__ float ew[KE][KTOT];
  __shared__ float al[KE];
  for (int e = 0; e < KE; ++e)
    for (int j = threadIdx.x; j < KTOT; j += 256)
      ew[e][j] = expert_w[((size_t)e*CO + o)*KTOT + j];   // [i*9+rs] order
  if (threadIdx.x < KE) al[threadIdx.x] = attn[b*KE + threadIdx.x];
  __syncthreads();
  for (int j2 = threadIdx.x; j2 < KTOT; j2 += 256) {
    int rs = j2 / 192, i = j2 - rs*192;
    float s = 0.f;
    #pragma unroll
    for (int e = 0; e < KE; ++e) s += al[e] * ew[e][i*9 + rs];
    w_re[((size_t)b*CO + o)*KTOT + j2] = (bf16)s;
  }
}

// ---------------- static conv2 weights, reordered [o][rs][i] bf16 ----------------
__global__ void k_w2re(const float* __restrict__ conv2_w, bf16* __restrict__ w2_re) {
  int o = blockIdx.x;
  __shared__ float cw[KTOT];
  for (int j = threadIdx.x; j < KTOT; j += 256) cw[j] = conv2_w[(size_t)o*KTOT + j];
  __syncthreads();
  for (int j2 = threadIdx.x; j2 < KTOT; j2 += 256) {
    int rs = j2 / 192, i = j2 - rs*192;
    w2_re[(size_t)o*KTOT + j2] = (bf16)cw[i*9 + rs];
  }
}

// ---------------- pack+pad x: f32 NCHW -> bf16 [b][i/8][130][130][8], zero borders ----------------
__global__ void k_xpack(const float* __restrict__ x, bf16* __restrict__ xpack) {
  int h2 = blockIdx.x, ib = blockIdx.y, b = blockIdx.z;
  size_t rowbase = (((size_t)b*24 + ib)*HP + h2)*HP;
  int t = threadIdx.x;  // 128
  if (h2 == 0 || h2 == HP-1) {
    uint4 z = make_uint4(0,0,0,0);
    for (int w = t; w < HP; w += 128) *(uint4*)(xpack + (rowbase + w)*8) = z;
    return;
  }
  __shared__ float tt[8][128];
  int h = h2 - 1;
  #pragma unroll
  for (int ii = 0; ii < 8; ++ii)
    tt[ii][t] = x[(((size_t)b*CI + ib*8 + ii)*H_ + h)*W_ + t];
  __syncthreads();
  bf16x8 v;
  #pragma unroll
  for (int ii = 0; ii < 8; ++ii) v[ii] = (bf16)tt[ii][t];
  *(bf16x8*)(xpack + (rowbase + t + 1)*8) = v;
  if (t == 0) {
    uint4 z = make_uint4(0,0,0,0);
    *(uint4*)(xpack + rowbase*8) = z;
    *(uint4*)(xpack + (rowbase + HP-1)*8) = z;
  }
}

// ---------------- zero borders of midpack ----------------
__global__ void k_midborder(bf16* __restrict__ midpack) {
  int bi = blockIdx.x;  // b*24+ib
  size_t base = (size_t)bi * HP * HP;
  uint4 z = make_uint4(0,0,0,0);
  for (int j = threadIdx.x; j < 516; j += 256) {
    int h2, w2;
    if (j < 130)      { h2 = 0;       w2 = j; }
    else if (j < 260) { h2 = 129;     w2 = j - 130; }
    else if (j < 388) { h2 = j - 259; w2 = 0; }
    else              { h2 = j - 387; w2 = 129; }
    *(uint4*)(midpack + (base + (size_t)h2*HP + w2)*8) = z;
  }
}

// ---------------- implicit-GEMM 3x3 conv, BM=192 x BN=256(2 rows) x BK=32 ----------------
// MODE 0: in=xpack, w per-batch, epilogue silu -> midpack (bf16 packed)
// MODE 1: in=midpack, w shared, epilogue silu + residual x -> out f32 NCHW
template<int MODE>
__global__ __launch_bounds__(512, 2)
void k_conv(const bf16* __restrict__ wre, const bf16* __restrict__ inpack,
            const float* __restrict__ bias_g, const float* __restrict__ xin,
            bf16* __restrict__ outpack, float* __restrict__ outp) {
  const int tid  = threadIdx.x;
  const int lane = tid & 63;
  const int wv   = tid >> 6;          // 0..7
  const int wm   = wv >> 2;           // 0..1 (o)
  const int wn   = wv & 3;            // 0..3 (p)
  const int l15  = lane & 15, l4 = lane >> 4;
  const int b    = blockIdx.y;
  const int tile = blockIdx.x;        // 0..63
  const int p0   = tile * 256;
  const int h0   = tile * 2;

  __shared__ __align__(16) bf16 Alds[2][CO*32];      // 24 KB
  __shared__ __align__(16) bf16 Blds[2][4*256*8];    // 32 KB
  __shared__ float bias_lds[CO];

  if (tid < CO) bias_lds[tid] = (MODE == 0) ? bias_g[b*CO + tid] : bias_g[tid];

  const size_t wbase = (MODE == 0) ? ((size_t)b*CO*KTOT) : 0;
  const size_t inb   = (size_t)b * 24;

  auto stage = [&](int t, int buf) {
    int rs = t / 6, ib = t - rs*6;
    int r = rs / 3, s = rs - r*3;
    int kbase = rs*192 + ib*32;
    // A tile [192][32] bf16: 12 chunks of 1024B (16 rows each)
    {
      int q = wv;
      int o = q*16 + (lane >> 2);
      gll16(wre + wbase + (size_t)o*KTOT + kbase + (lane & 3)*8,
            &Alds[buf][q*16*32]);
    }
    if (wv < 4) {
      int q = 8 + wv;
      int o = q*16 + (lane >> 2);
      gll16(wre + wbase + (size_t)o*KTOT + kbase + (lane & 3)*8,
            &Alds[buf][q*16*32]);
    }
    // B tile [kg=4][p=256][8] bf16: 16 chunks of 1024B
    #pragma unroll
    for (int c = 0; c < 2; ++c) {
      int q  = wv*2 + c;
      int kg = q >> 2, pc = q & 3;
      int p  = pc*64 + lane;
      int hh = h0 + (p >> 7) + r;      // 0..129 (padded, always valid)
      int ww = (p & 127) + s;          // 0..129
      size_t srcoff = (((inb + (size_t)(ib*4 + kg))*HP + hh)*HP + ww)*8;
      gll16(inpack + srcoff, &Blds[buf][(kg*256 + pc*64)*8]);
    }
  };

  f32x4 acc[6][4];
  #pragma unroll
  for (int mf = 0; mf < 6; ++mf)
    #pragma unroll
    for (int nf = 0; nf < 4; ++nf)
      #pragma unroll
      for (int jj = 0; jj < 4; ++jj) acc[mf][nf][jj] = 0.f;

  stage(0, 0);
  __syncthreads();

  for (int t = 0; t < 54; ++t) {
    int cbuf = t & 1;
    if (t + 1 < 54) stage(t + 1, cbuf ^ 1);
    const bf16* A  = Alds[cbuf];
    const bf16* Bp = Blds[cbuf];
    bf16x8 af[6];
    #pragma unroll
    for (int mf = 0; mf < 6; ++mf)
      af[mf] = *(const bf16x8*)(A + (wm*96 + mf*16 + l15)*32 + l4*8);
    #pragma unroll
    for (int nf = 0; nf < 4; ++nf) {
      bf16x8 bv = *(const bf16x8*)(Bp + (size_t)(l4*256 + wn*64 + nf*16 + l15)*8);
      #pragma unroll
      for (int mf = 0; mf < 6; ++mf)
        acc[mf][nf] = __builtin_amdgcn_mfma_f32_16x16x32_bf16(af[mf], bv, acc[mf][nf], 0, 0, 0);
    }
    __syncthreads();
  }

  // epilogue
  #pragma unroll
  for (int mf = 0; mf < 6; ++mf) {
    int ob = wm*96 + mf*16 + l4*4;     // output channel base (4 consecutive)
    #pragma unroll
    for (int nf = 0; nf < 4; ++nf) {
      int pl = wn*64 + nf*16 + l15;
      int p  = p0 + pl;
      f32x4 v = acc[mf][nf];
      if (MODE == 0) {
        int h = p >> 7, w = p & 127;
        bf16x4 pk;
        #pragma unroll
        for (int jj = 0; jj < 4; ++jj) {
          float xv = v[jj] + bias_lds[ob + jj];
          pk[jj] = (bf16)silu_f(xv);
        }
        size_t basep = (((size_t)b*24 + (ob >> 3))*HP + (h + 1))*HP + (w + 1);
        *(bf16x4*)(outpack + basep*8 + (ob & 7)) = pk;
      } else {
        #pragma unroll
        for (int jj = 0; jj < 4; ++jj) {
          float xv = silu_f(v[jj] + bias_lds[ob + jj]);
          size_t idx = ((size_t)b*CO + ob + jj)*NPX + p;
          outp[idx] = xv + xin[idx];
        }
      }
    }
  }
}

extern "C" void kernel_launch(void* const* d_in, const int* in_sizes, int n_in,
                              void* d_out, int out_size, void* d_ws, size_t ws_size,
                              hipStream_t stream) {
  const float* x        = (const float*)d_in[0];
  const float* latent   = (const float*)d_in[1];
  const float* expert_w = (const float*)d_in[2];
  const float* expert_b = (const float*)d_in[3];
  const float* attn_w   = (const float*)d_in[4];
  const float* attn_b   = (const float*)d_in[5];
  const float* conv2_w  = (const float*)d_in[6];
  const float* conv2_b  = (const float*)d_in[7];
  float* outp = (float*)d_out;

  char* base = (char*)d_ws;
  size_t off = 0;
  float* attn = (float*)(base + off); off += 4096;
  float* bdyn = (float*)(base + off); off += 16384;
  bf16* w_re  = (bf16*)(base + off);  off += (size_t)B_*CO*KTOT*2;      // 10.6 MB
  bf16* w2_re = (bf16*)(base + off);  off += (size_t)CO*KTOT*2;         // 0.66 MB
  bf16* xpack = (bf16*)(base + off);  off += (size_t)B_*24*HP*HP*8*2;   // 103.8 MB
  bf16* midpack = (bf16*)(base + off); off += (size_t)B_*24*HP*HP*8*2;  // 103.8 MB
  (void)ws_size; (void)in_sizes; (void)n_in; (void)out_size;

  k_attn<<<dim3(1), dim3(128), 0, stream>>>(latent, attn_w, attn_b, attn);
  k_bdyn<<<dim3(12), dim3(256), 0, stream>>>(attn, expert_b, bdyn);
  k_wdyn<<<dim3(CO*B_), dim3(256), 0, stream>>>(expert_w, attn, w_re);
  k_w2re<<<dim3(CO), dim3(256), 0, stream>>>(conv2_w, w2_re);
  k_xpack<<<dim3(130, 24, 16), dim3(128), 0, stream>>>(x, xpack);
  k_midborder<<<dim3(B_*24), dim3(256), 0, stream>>>(midpack);
  k_conv<0><<<dim3(64, 16), dim3(512), 0, stream>>>(w_re, xpack, bdyn, x, midpack, outp);
  k_conv<1><<<dim3(64, 16), dim3(512), 0, stream>>>(w2_re, midpack, conv2_b, x, midpack, outp);
}

// Round 2
// 658.054 us; speedup vs baseline: 1.1288x; 1.1288x over previous
//
#include <hip/hip_runtime.h>
#include <stdint.h>

typedef __bf16 bf16;
typedef bf16 bf16x8 __attribute__((ext_vector_type(8)));
typedef bf16 bf16x4 __attribute__((ext_vector_type(4)));
typedef float f32x4 __attribute__((ext_vector_type(4)));

#define B_   16
#define CI   192
#define CO   192
#define H_   128
#define W_   128
#define KE   8
#define LD   64
#define KTOT 1728   // 9*192
#define HP   130    // padded H/W
#define HPHP (HP*HP)
#define NPX  (H_*W_)
#define NT   54     // K-steps of 32

__device__ __forceinline__ void gll16(const void* g, void* l) {
  __builtin_amdgcn_global_load_lds(
      (const __attribute__((address_space(1))) unsigned int*)g,
      (__attribute__((address_space(3))) unsigned int*)l, 16, 0, 0);
}

__device__ __forceinline__ float silu_f(float x) {
  return x / (1.f + __expf(-x));
}

// ---------------- attention softmax: latent[16,64] -> attn[16,8] ----------------
__global__ void k_attn(const float* __restrict__ latent, const float* __restrict__ attn_w,
                       const float* __restrict__ attn_b, float* __restrict__ attn) {
  int t = threadIdx.x;           // 128 threads: b = t>>3, k = t&7
  int b = t >> 3, k = t & 7;
  float s = attn_b[k];
  for (int d = 0; d < LD; ++d) s += latent[b*LD + d] * attn_w[k*LD + d];
  float m = s;
  for (int off = 4; off; off >>= 1) m = fmaxf(m, __shfl_xor(m, off, 8));
  float e = __expf(s - m);
  float sum = e;
  for (int off = 4; off; off >>= 1) sum += __shfl_xor(sum, off, 8);
  attn[t] = e / sum;
}

// ---------------- dynamic bias ----------------
__global__ void k_bdyn(const float* __restrict__ attn, const float* __restrict__ expert_b,
                       float* __restrict__ bdyn) {
  int j = blockIdx.x * 256 + threadIdx.x;
  if (j >= B_ * CO) return;
  int b = j / CO, o = j - b * CO;
  float s = 0.f;
  #pragma unroll
  for (int e = 0; e < KE; ++e) s += attn[b*KE + e] * expert_b[e*CO + o];
  bdyn[j] = s;
}

// ---------------- dynamic weights -> staged layout [b][kt=54][chunk=12][slot=64][8] bf16
// slot L holds logical (row = L>>2, kslot = (L&3)^((L>>3)&3)); o = chunk*16+row,
// logical k = kt*32 + kslot*8 + j; (rs = k/192, i = k%192); value = sum_e attn*w[e][o][i][rs]
__global__ void k_wdyn(const float* __restrict__ expert_w, const float* __restrict__ attn,
                       bf16* __restrict__ w_re) {
  int o = blockIdx.x;            // 192
  int chunk = o >> 4, row = o & 15, c = (row >> 1) & 3;
  __shared__ float ew[KE][KTOT];
  __shared__ float al[B_][KE];
  for (int e = 0; e < KE; ++e)
    for (int j = threadIdx.x; j < KTOT; j += 256)
      ew[e][j] = expert_w[((size_t)e*CO + o)*KTOT + j];   // [i*9+rs]
  if (threadIdx.x < B_*KE) al[threadIdx.x >> 3][threadIdx.x & 7] = attn[threadIdx.x];
  __syncthreads();
  for (int idx = threadIdx.x; idx < B_*KTOT; idx += 256) {
    int b = idx / KTOT, k = idx - b*KTOT;
    int rs = k / 192, i = k - rs*192;
    float s = 0.f;
    #pragma unroll
    for (int e = 0; e < KE; ++e) s += al[b][e] * ew[e][i*9 + rs];
    int kt = k >> 5, kslot = (k >> 3) & 3, j = k & 7;
    int slot = row*4 + (kslot ^ c);
    w_re[((((size_t)b*NT + kt)*12 + chunk)*64 + slot)*8 + j] = (bf16)s;
  }
}

// ---------------- static conv2 weights -> same staged layout (no b) ----------------
__global__ void k_w2re(const float* __restrict__ conv2_w, bf16* __restrict__ w2_re) {
  int o = blockIdx.x;
  int chunk = o >> 4, row = o & 15, c = (row >> 1) & 3;
  __shared__ float cw[KTOT];
  for (int j = threadIdx.x; j < KTOT; j += 256) cw[j] = conv2_w[(size_t)o*KTOT + j];
  __syncthreads();
  for (int k = threadIdx.x; k < KTOT; k += 256) {
    int rs = k / 192, i = k - rs*192;
    int kt = k >> 5, kslot = (k >> 3) & 3, j = k & 7;
    int slot = row*4 + (kslot ^ c);
    w2_re[(((size_t)kt*12 + chunk)*64 + slot)*8 + j] = (bf16)cw[i*9 + rs];
  }
}

// ---------------- pack+pad x: f32 NCHW -> bf16 [b][i/8][130][130][8], zero borders ----------------
__global__ void k_xpack(const float* __restrict__ x, bf16* __restrict__ xpack) {
  int h2 = blockIdx.x, ib = blockIdx.y, b = blockIdx.z;
  size_t rowbase = (((size_t)b*24 + ib)*HP + h2)*HP;
  int t = threadIdx.x;  // 128
  if (h2 == 0 || h2 == HP-1) {
    uint4 z = make_uint4(0,0,0,0);
    for (int w = t; w < HP; w += 128) *(uint4*)(xpack + (rowbase + w)*8) = z;
    return;
  }
  __shared__ float tt[8][128];
  int h = h2 - 1;
  #pragma unroll
  for (int ii = 0; ii < 8; ++ii)
    tt[ii][t] = x[(((size_t)b*CI + ib*8 + ii)*H_ + h)*W_ + t];
  __syncthreads();
  bf16x8 v;
  #pragma unroll
  for (int ii = 0; ii < 8; ++ii) v[ii] = (bf16)tt[ii][t];
  *(bf16x8*)(xpack + (rowbase + t + 1)*8) = v;
  if (t == 0) {
    uint4 z = make_uint4(0,0,0,0);
    *(uint4*)(xpack + rowbase*8) = z;
    *(uint4*)(xpack + (rowbase + HP-1)*8) = z;
  }
}

// ---------------- zero borders of midpack ----------------
__global__ void k_midborder(bf16* __restrict__ midpack) {
  int bi = blockIdx.x;  // b*24+ib
  size_t base = (size_t)bi * HPHP;
  uint4 z = make_uint4(0,0,0,0);
  for (int j = threadIdx.x; j < 516; j += 256) {
    int h2, w2;
    if (j < 130)      { h2 = 0;       w2 = j; }
    else if (j < 260) { h2 = 129;     w2 = j - 130; }
    else if (j < 388) { h2 = j - 259; w2 = 0; }
    else              { h2 = j - 387; w2 = 129; }
    *(uint4*)(midpack + (base + (size_t)h2*HP + w2)*8) = z;
  }
}

// ---------------- implicit-GEMM 3x3 conv, BM=192 x BN=256(2 rows) x BK=32 ----------------
template<int MODE>
__global__ __launch_bounds__(512, 2)
void k_conv(const bf16* __restrict__ wre, const bf16* __restrict__ inpack,
            const float* __restrict__ bias_g, const float* __restrict__ xin,
            bf16* __restrict__ outpack, float* __restrict__ outp) {
  const int tid  = threadIdx.x;
  const int lane = tid & 63;
  const int wv   = tid >> 6;          // 0..7
  const int wm   = wv >> 2;           // 0..1 (o half)
  const int wn   = wv & 3;            // 0..3 (p quarter)
  const int l15  = lane & 15, l4 = lane >> 4;

  // XCD-aware chunked remap: 1024 blocks, 128/XCD => each XCD owns 2 batches
  const int bid  = blockIdx.x;
  const int n    = (bid & 7) * 128 + (bid >> 3);
  const int b    = n >> 6;
  const int tile = n & 63;
  const int p0   = tile * 256;
  const int h0   = tile * 2;

  __shared__ __align__(16) bf16 Alds[2][12*512];   // 24 KB
  __shared__ __align__(16) bf16 Blds[2][16*512];   // 32 KB
  __shared__ float bias_lds[CO];

  if (tid < CO) bias_lds[tid] = (MODE == 0) ? bias_g[b*CO + tid] : bias_g[tid];

  const size_t wbase = (MODE == 0) ? ((size_t)b*CO*KTOT) : 0;

  // ---- staging state (strength-reduced) ----
  // A layout: [kt][chunk=12][slot=64][8]; per-step advance = 12*64*8 = 6144
  const bf16* a0 = wre + wbase + ((size_t)(wv    )*64 + lane)*8;
  const bf16* a1 = wre + wbase + ((size_t)(8 + wv)*64 + lane)*8;
  // B chunks: q = wv*2+c, kg=q>>2, pc=q&3; p = pc*64+lane
  const int q0 = wv*2, q1 = wv*2 + 1;
  const int kg0 = q0 >> 2, pc0 = q0 & 3, p_0 = pc0*64 + lane;
  const int kg1 = q1 >> 2, pc1 = q1 & 3, p_1 = pc1*64 + lane;
  const bf16* bsrc0 = inpack + ((((size_t)b*24 + kg0)*HP + h0 + (p_0 >> 7))*HP + (p_0 & 127))*8;
  const bf16* bsrc1 = inpack + ((((size_t)b*24 + kg1)*HP + h0 + (p_1 >> 7))*HP + (p_1 & 127))*8;

  int rsn = 0, ibn = 0, boff = 0;   // next-stage indices / B element offset

  auto STAGE = [&](int bufbit) {
    bf16* A0 = bufbit ? &Alds[1][wv*512]       : &Alds[0][wv*512];
    bf16* A1 = bufbit ? &Alds[1][(8+wv)*512]   : &Alds[0][(8+wv)*512];
    bf16* B0 = bufbit ? &Blds[1][q0*512]       : &Blds[0][q0*512];
    bf16* B1 = bufbit ? &Blds[1][q1*512]       : &Blds[0][q1*512];
    gll16(a0, A0);
    if (wv < 4) gll16(a1, A1);
    gll16(bsrc0 + boff, B0);
    gll16(bsrc1 + boff, B1);
    a0 += 6144; a1 += 6144;
    if (++ibn == 6) {
      ibn = 0; ++rsn;
      boff += (((rsn % 3) == 0) ? (HP - 2) : 1) * 8 - 20*HPHP*8;
    } else {
      boff += 4*HPHP*8;
    }
  };

  f32x4 acc[6][4];
  #pragma unroll
  for (int mf = 0; mf < 6; ++mf)
    #pragma unroll
    for (int nf = 0; nf < 4; ++nf)
      #pragma unroll
      for (int jj = 0; jj < 4; ++jj) acc[mf][nf][jj] = 0.f;

  const int sw = l15*4 + (l4 ^ ((l15 >> 1) & 3));   // swizzled A slot (2-way, free)

  STAGE(0);

  for (int t = 0; t < NT; ++t) {
    if (t < NT-1) {
      STAGE((t+1) & 1);
      // drain iter-t loads, keep iter-(t+1)'s in flight
      if (wv < 4) asm volatile("s_waitcnt vmcnt(4)" ::: "memory");
      else        asm volatile("s_waitcnt vmcnt(3)" ::: "memory");
    } else {
      asm volatile("s_waitcnt vmcnt(0)" ::: "memory");
    }
    __builtin_amdgcn_sched_barrier(0);
    asm volatile("s_barrier" ::: "memory");

    const bf16* A  = Alds[t & 1];
    const bf16* Bp = Blds[t & 1];
    bf16x8 af[6];
    #pragma unroll
    for (int mf = 0; mf < 6; ++mf)
      af[mf] = *(const bf16x8*)(A + (wm*6 + mf)*512 + sw*8);
    __builtin_amdgcn_s_setprio(1);
    #pragma unroll
    for (int nf = 0; nf < 4; ++nf) {
      bf16x8 bv = *(const bf16x8*)(Bp + (l4*4 + wn)*512 + nf*128 + l15*8);
      #pragma unroll
      for (int mf = 0; mf < 6; ++mf)
        acc[mf][nf] = __builtin_amdgcn_mfma_f32_16x16x32_bf16(af[mf], bv, acc[mf][nf], 0, 0, 0);
    }
    __builtin_amdgcn_s_setprio(0);
    asm volatile("s_barrier" ::: "memory");   // reads of buf[t&1] done before next stage overwrites
  }

  // epilogue
  #pragma unroll
  for (int mf = 0; mf < 6; ++mf) {
    int ob = wm*96 + mf*16 + l4*4;     // output channel base (4 consecutive)
    #pragma unroll
    for (int nf = 0; nf < 4; ++nf) {
      int pl = wn*64 + nf*16 + l15;
      int p  = p0 + pl;
      f32x4 v = acc[mf][nf];
      if (MODE == 0) {
        int h = p >> 7, w = p & 127;
        bf16x4 pk;
        #pragma unroll
        for (int jj = 0; jj < 4; ++jj) {
          float xv = v[jj] + bias_lds[ob + jj];
          pk[jj] = (bf16)silu_f(xv);
        }
        size_t basep = (((size_t)b*24 + (ob >> 3))*HP + (h + 1))*HP + (w + 1);
        *(bf16x4*)(outpack + basep*8 + (ob & 7)) = pk;
      } else {
        #pragma unroll
        for (int jj = 0; jj < 4; ++jj) {
          float xv = silu_f(v[jj] + bias_lds[ob + jj]);
          size_t idx = ((size_t)b*CO + ob + jj)*NPX + p;
          outp[idx] = xv + xin[idx];
        }
      }
    }
  }
}

extern "C" void kernel_launch(void* const* d_in, const int* in_sizes, int n_in,
                              void* d_out, int out_size, void* d_ws, size_t ws_size,
                              hipStream_t stream) {
  const float* x        = (const float*)d_in[0];
  const float* latent   = (const float*)d_in[1];
  const float* expert_w = (const float*)d_in[2];
  const float* expert_b = (const float*)d_in[3];
  const float* attn_w   = (const float*)d_in[4];
  const float* attn_b   = (const float*)d_in[5];
  const float* conv2_w  = (const float*)d_in[6];
  const float* conv2_b  = (const float*)d_in[7];
  float* outp = (float*)d_out;

  char* base = (char*)d_ws;
  size_t off = 0;
  float* attn = (float*)(base + off); off += 4096;
  float* bdyn = (float*)(base + off); off += 16384;
  bf16* w_re  = (bf16*)(base + off);  off += (size_t)B_*CO*KTOT*2;      // 10.6 MB
  bf16* w2_re = (bf16*)(base + off);  off += (size_t)CO*KTOT*2;         // 0.66 MB
  bf16* xpack = (bf16*)(base + off);  off += (size_t)B_*24*HPHP*8*2;    // 103.8 MB
  bf16* midpack = (bf16*)(base + off); off += (size_t)B_*24*HPHP*8*2;   // 103.8 MB
  (void)ws_size; (void)in_sizes; (void)n_in; (void)out_size;

  k_attn<<<dim3(1), dim3(128), 0, stream>>>(latent, attn_w, attn_b, attn);
  k_bdyn<<<dim3(12), dim3(256), 0, stream>>>(attn, expert_b, bdyn);
  k_wdyn<<<dim3(CO), dim3(256), 0, stream>>>(expert_w, attn, w_re);
  k_w2re<<<dim3(CO), dim3(256), 0, stream>>>(conv2_w, w2_re);
  k_xpack<<<dim3(130, 24, 16), dim3(128), 0, stream>>>(x, xpack);
  k_midborder<<<dim3(B_*24), dim3(256), 0, stream>>>(midpack);
  k_conv<0><<<dim3(1024), dim3(512), 0, stream>>>(w_re, xpack, bdyn, x, midpack, outp);
  k_conv<1><<<dim3(1024), dim3(512), 0, stream>>>(w2_re, midpack, conv2_b, x, midpack, outp);
}

// Round 3
// 648.386 us; speedup vs baseline: 1.1456x; 1.0149x over previous
//
#include <hip/hip_runtime.h>
#include <stdint.h>

typedef __bf16 bf16;
typedef bf16 bf16x8 __attribute__((ext_vector_type(8)));
typedef bf16 bf16x4 __attribute__((ext_vector_type(4)));
typedef float f32x4 __attribute__((ext_vector_type(4)));

#define B_   16
#define CI   192
#define CO   192
#define H_   128
#define W_   128
#define KE   8
#define LD   64
#define KTOT 1728   // 9*192
#define HP   130    // padded H/W
#define HPHP (HP*HP)
#define NPX  (H_*W_)
#define NT   54     // K-steps of 32

__device__ __forceinline__ void gll16(const void* g, void* l) {
  __builtin_amdgcn_global_load_lds(
      (const __attribute__((address_space(1))) unsigned int*)g,
      (__attribute__((address_space(3))) unsigned int*)l, 16, 0, 0);
}

__device__ __forceinline__ float silu_f(float x) {
  return x / (1.f + __expf(-x));
}

// ---------------- attention softmax: latent[16,64] -> attn[16,8] ----------------
__global__ void k_attn(const float* __restrict__ latent, const float* __restrict__ attn_w,
                       const float* __restrict__ attn_b, float* __restrict__ attn) {
  int t = threadIdx.x;           // 128 threads: b = t>>3, k = t&7
  int b = t >> 3, k = t & 7;
  float s = attn_b[k];
  for (int d = 0; d < LD; ++d) s += latent[b*LD + d] * attn_w[k*LD + d];
  float m = s;
  for (int off = 4; off; off >>= 1) m = fmaxf(m, __shfl_xor(m, off, 8));
  float e = __expf(s - m);
  float sum = e;
  for (int off = 4; off; off >>= 1) sum += __shfl_xor(sum, off, 8);
  attn[t] = e / sum;
}

// ---------------- dynamic bias ----------------
__global__ void k_bdyn(const float* __restrict__ attn, const float* __restrict__ expert_b,
                       float* __restrict__ bdyn) {
  int j = blockIdx.x * 256 + threadIdx.x;
  if (j >= B_ * CO) return;
  int b = j / CO, o = j - b * CO;
  float s = 0.f;
  #pragma unroll
  for (int e = 0; e < KE; ++e) s += attn[b*KE + e] * expert_b[e*CO + o];
  bdyn[j] = s;
}

// ---------------- dynamic weights -> staged layout [b][kt=54][chunk=12][slot=64][8] bf16
__global__ void k_wdyn(const float* __restrict__ expert_w, const float* __restrict__ attn,
                       bf16* __restrict__ w_re) {
  int o = blockIdx.x;            // 192
  int chunk = o >> 4, row = o & 15, c = (row >> 1) & 3;
  __shared__ float ew[KE][KTOT];
  __shared__ float al[B_][KE];
  for (int e = 0; e < KE; ++e)
    for (int j = threadIdx.x; j < KTOT; j += 256)
      ew[e][j] = expert_w[((size_t)e*CO + o)*KTOT + j];   // [i*9+rs]
  if (threadIdx.x < B_*KE) al[threadIdx.x >> 3][threadIdx.x & 7] = attn[threadIdx.x];
  __syncthreads();
  for (int idx = threadIdx.x; idx < B_*KTOT; idx += 256) {
    int b = idx / KTOT, k = idx - b*KTOT;
    int rs = k / 192, i = k - rs*192;
    float s = 0.f;
    #pragma unroll
    for (int e = 0; e < KE; ++e) s += al[b][e] * ew[e][i*9 + rs];
    int kt = k >> 5, kslot = (k >> 3) & 3, j = k & 7;
    int slot = row*4 + (kslot ^ c);
    w_re[((((size_t)b*NT + kt)*12 + chunk)*64 + slot)*8 + j] = (bf16)s;
  }
}

// ---------------- static conv2 weights -> same staged layout (no b) ----------------
__global__ void k_w2re(const float* __restrict__ conv2_w, bf16* __restrict__ w2_re) {
  int o = blockIdx.x;
  int chunk = o >> 4, row = o & 15, c = (row >> 1) & 3;
  __shared__ float cw[KTOT];
  for (int j = threadIdx.x; j < KTOT; j += 256) cw[j] = conv2_w[(size_t)o*KTOT + j];
  __syncthreads();
  for (int k = threadIdx.x; k < KTOT; k += 256) {
    int rs = k / 192, i = k - rs*192;
    int kt = k >> 5, kslot = (k >> 3) & 3, j = k & 7;
    int slot = row*4 + (kslot ^ c);
    w2_re[(((size_t)kt*12 + chunk)*64 + slot)*8 + j] = (bf16)cw[i*9 + rs];
  }
}

// ---------------- pack+pad x: f32 NCHW -> bf16 [b][i/8][130][130][8], zero borders ----------------
__global__ void k_xpack(const float* __restrict__ x, bf16* __restrict__ xpack) {
  int h2 = blockIdx.x, ib = blockIdx.y, b = blockIdx.z;
  size_t rowbase = (((size_t)b*24 + ib)*HP + h2)*HP;
  int t = threadIdx.x;  // 128
  if (h2 == 0 || h2 == HP-1) {
    uint4 z = make_uint4(0,0,0,0);
    for (int w = t; w < HP; w += 128) *(uint4*)(xpack + (rowbase + w)*8) = z;
    return;
  }
  __shared__ float tt[8][128];
  int h = h2 - 1;
  #pragma unroll
  for (int ii = 0; ii < 8; ++ii)
    tt[ii][t] = x[(((size_t)b*CI + ib*8 + ii)*H_ + h)*W_ + t];
  __syncthreads();
  bf16x8 v;
  #pragma unroll
  for (int ii = 0; ii < 8; ++ii) v[ii] = (bf16)tt[ii][t];
  *(bf16x8*)(xpack + (rowbase + t + 1)*8) = v;
  if (t == 0) {
    uint4 z = make_uint4(0,0,0,0);
    *(uint4*)(xpack + rowbase*8) = z;
    *(uint4*)(xpack + (rowbase + HP-1)*8) = z;
  }
}

// ---------------- zero borders of midpack ----------------
__global__ void k_midborder(bf16* __restrict__ midpack) {
  int bi = blockIdx.x;  // b*24+ib
  size_t base = (size_t)bi * HPHP;
  uint4 z = make_uint4(0,0,0,0);
  for (int j = threadIdx.x; j < 516; j += 256) {
    int h2, w2;
    if (j < 130)      { h2 = 0;       w2 = j; }
    else if (j < 260) { h2 = 129;     w2 = j - 130; }
    else if (j < 388) { h2 = j - 259; w2 = 0; }
    else              { h2 = j - 387; w2 = 129; }
    *(uint4*)(midpack + (base + (size_t)h2*HP + w2)*8) = z;
  }
}

// ---------------- implicit-GEMM 3x3 conv, BM=192 x BN=256(2 rows) x BK=32 ----------------
// 3-MFMA-phase interleaved schedule (T3+T4+T5): per K-step
//   entry: vmcnt(0) + barrier   (prev step's staging landed; had a full step in flight)
//   P1: dsr bv0-3,af0,af1 ; stage A(t+1)  ; BAR ; lgkm(0) ; prio1 ; 8 MFMA ; prio0
//   P2: dsr af2,af3       ; stage B0(t+1) ; BAR ; lgkm(0) ; prio1 ; 8 MFMA ; prio0
//   P3: dsr af4,af5       ; stage B1(t+1) ; BAR ; lgkm(0) ; prio1 ; 8 MFMA ; prio0
template<int MODE>
__global__ __launch_bounds__(512, 2)
void k_conv(const bf16* __restrict__ wre, const bf16* __restrict__ inpack,
            const float* __restrict__ bias_g, const float* __restrict__ xin,
            bf16* __restrict__ outpack, float* __restrict__ outp) {
  const int tid  = threadIdx.x;
  const int lane = tid & 63;
  const int wv   = tid >> 6;          // 0..7
  const int wm   = wv >> 2;           // 0..1 (o half)
  const int wn   = wv & 3;            // 0..3 (p quarter)
  const int l15  = lane & 15, l4 = lane >> 4;

  // XCD-aware chunked remap: 1024 blocks, 128/XCD => each XCD owns 2 batches
  const int bid  = blockIdx.x;
  const int n    = (bid & 7) * 128 + (bid >> 3);
  const int b    = n >> 6;
  const int tile = n & 63;
  const int p0   = tile * 256;
  const int h0   = tile * 2;

  __shared__ __align__(16) bf16 Alds[2][12*512];   // 24 KB
  __shared__ __align__(16) bf16 Blds[2][16*512];   // 32 KB
  __shared__ float bias_lds[CO];

  if (tid < CO) bias_lds[tid] = (MODE == 0) ? bias_g[b*CO + tid] : bias_g[tid];

  const size_t wbase = (MODE == 0) ? ((size_t)b*CO*KTOT) : 0;

  // ---- staging state (strength-reduced) ----
  const bf16* a0 = wre + wbase + ((size_t)(wv    )*64 + lane)*8;
  const bf16* a1 = wre + wbase + ((size_t)(8 + wv)*64 + lane)*8;
  const int q0 = wv*2, q1 = wv*2 + 1;
  const int kg0 = q0 >> 2, pc0 = q0 & 3, p_0 = pc0*64 + lane;
  const int kg1 = q1 >> 2, pc1 = q1 & 3, p_1 = pc1*64 + lane;
  const bf16* bsrc0 = inpack + ((((size_t)b*24 + kg0)*HP + h0 + (p_0 >> 7))*HP + (p_0 & 127))*8;
  const bf16* bsrc1 = inpack + ((((size_t)b*24 + kg1)*HP + h0 + (p_1 >> 7))*HP + (p_1 & 127))*8;

  int rsn = 0, ibn = 0, boff = 0;

  f32x4 acc[6][4];
  #pragma unroll
  for (int mf = 0; mf < 6; ++mf)
    #pragma unroll
    for (int nf = 0; nf < 4; ++nf)
      #pragma unroll
      for (int jj = 0; jj < 4; ++jj) acc[mf][nf][jj] = 0.f;

  const int sw = l15*4 + (l4 ^ ((l15 >> 1) & 3));   // swizzled A slot (2-way, free)

  // prologue: stage buffer 0 fully
  {
    gll16(a0, &Alds[0][wv*512]);
    if (wv < 4) gll16(a1, &Alds[0][(8+wv)*512]);
    gll16(bsrc0, &Blds[0][q0*512]);
    gll16(bsrc1, &Blds[0][q1*512]);
    a0 += 6144; a1 += 6144;
    ibn = 1; boff = 4*HPHP*8;
  }

  for (int t = 0; t < NT; ++t) {
    const bf16* A   = Alds[t & 1];
    const bf16* Bp  = Blds[t & 1];
    bf16* An  = (bf16*)Alds[(t+1) & 1];
    bf16* Bn  = (bf16*)Blds[(t+1) & 1];
    const bool pre  = (t + 1 < NT);
    const bf16* brow = Bp + (size_t)(l4*4 + wn)*512 + l15*8;

    // ---- step entry: all waves' staging for buf cur has landed ----
    asm volatile("s_waitcnt vmcnt(0)" ::: "memory");
    __builtin_amdgcn_s_barrier();

    // ---- P1 ----
    bf16x8 bv0 = *(const bf16x8*)(brow);
    bf16x8 bv1 = *(const bf16x8*)(brow + 128);
    bf16x8 bv2 = *(const bf16x8*)(brow + 256);
    bf16x8 bv3 = *(const bf16x8*)(brow + 384);
    bf16x8 af0 = *(const bf16x8*)(A + (wm*6 + 0)*512 + sw*8);
    bf16x8 af1 = *(const bf16x8*)(A + (wm*6 + 1)*512 + sw*8);
    if (pre) {
      gll16(a0, An + wv*512);
      if (wv < 4) gll16(a1, An + (8+wv)*512);
      a0 += 6144; a1 += 6144;
    }
    __builtin_amdgcn_s_barrier();
    asm volatile("s_waitcnt lgkmcnt(0)" ::: "memory");
    __builtin_amdgcn_s_setprio(1);
    acc[0][0] = __builtin_amdgcn_mfma_f32_16x16x32_bf16(af0, bv0, acc[0][0], 0, 0, 0);
    acc[0][1] = __builtin_amdgcn_mfma_f32_16x16x32_bf16(af0, bv1, acc[0][1], 0, 0, 0);
    acc[0][2] = __builtin_amdgcn_mfma_f32_16x16x32_bf16(af0, bv2, acc[0][2], 0, 0, 0);
    acc[0][3] = __builtin_amdgcn_mfma_f32_16x16x32_bf16(af0, bv3, acc[0][3], 0, 0, 0);
    acc[1][0] = __builtin_amdgcn_mfma_f32_16x16x32_bf16(af1, bv0, acc[1][0], 0, 0, 0);
    acc[1][1] = __builtin_amdgcn_mfma_f32_16x16x32_bf16(af1, bv1, acc[1][1], 0, 0, 0);
    acc[1][2] = __builtin_amdgcn_mfma_f32_16x16x32_bf16(af1, bv2, acc[1][2], 0, 0, 0);
    acc[1][3] = __builtin_amdgcn_mfma_f32_16x16x32_bf16(af1, bv3, acc[1][3], 0, 0, 0);
    __builtin_amdgcn_s_setprio(0);

    // ---- P2 ----
    bf16x8 af2 = *(const bf16x8*)(A + (wm*6 + 2)*512 + sw*8);
    bf16x8 af3 = *(const bf16x8*)(A + (wm*6 + 3)*512 + sw*8);
    if (pre) gll16(bsrc0 + boff, Bn + q0*512);
    __builtin_amdgcn_s_barrier();
    asm volatile("s_waitcnt lgkmcnt(0)" ::: "memory");
    __builtin_amdgcn_s_setprio(1);
    acc[2][0] = __builtin_amdgcn_mfma_f32_16x16x32_bf16(af2, bv0, acc[2][0], 0, 0, 0);
    acc[2][1] = __builtin_amdgcn_mfma_f32_16x16x32_bf16(af2, bv1, acc[2][1], 0, 0, 0);
    acc[2][2] = __builtin_amdgcn_mfma_f32_16x16x32_bf16(af2, bv2, acc[2][2], 0, 0, 0);
    acc[2][3] = __builtin_amdgcn_mfma_f32_16x16x32_bf16(af2, bv3, acc[2][3], 0, 0, 0);
    acc[3][0] = __builtin_amdgcn_mfma_f32_16x16x32_bf16(af3, bv0, acc[3][0], 0, 0, 0);
    acc[3][1] = __builtin_amdgcn_mfma_f32_16x16x32_bf16(af3, bv1, acc[3][1], 0, 0, 0);
    acc[3][2] = __builtin_amdgcn_mfma_f32_16x16x32_bf16(af3, bv2, acc[3][2], 0, 0, 0);
    acc[3][3] = __builtin_amdgcn_mfma_f32_16x16x32_bf16(af3, bv3, acc[3][3], 0, 0, 0);
    __builtin_amdgcn_s_setprio(0);

    // ---- P3 ----
    bf16x8 af4 = *(const bf16x8*)(A + (wm*6 + 4)*512 + sw*8);
    bf16x8 af5 = *(const bf16x8*)(A + (wm*6 + 5)*512 + sw*8);
    if (pre) {
      gll16(bsrc1 + boff, Bn + q1*512);
      if (++ibn == 6) {
        ibn = 0; ++rsn;
        boff += (((rsn % 3) == 0) ? (HP - 2) : 1) * 8 - 20*HPHP*8;
      } else {
        boff += 4*HPHP*8;
      }
    }
    __builtin_amdgcn_s_barrier();
    asm volatile("s_waitcnt lgkmcnt(0)" ::: "memory");
    __builtin_amdgcn_s_setprio(1);
    acc[4][0] = __builtin_amdgcn_mfma_f32_16x16x32_bf16(af4, bv0, acc[4][0], 0, 0, 0);
    acc[4][1] = __builtin_amdgcn_mfma_f32_16x16x32_bf16(af4, bv1, acc[4][1], 0, 0, 0);
    acc[4][2] = __builtin_amdgcn_mfma_f32_16x16x32_bf16(af4, bv2, acc[4][2], 0, 0, 0);
    acc[4][3] = __builtin_amdgcn_mfma_f32_16x16x32_bf16(af4, bv3, acc[4][3], 0, 0, 0);
    acc[5][0] = __builtin_amdgcn_mfma_f32_16x16x32_bf16(af5, bv0, acc[5][0], 0, 0, 0);
    acc[5][1] = __builtin_amdgcn_mfma_f32_16x16x32_bf16(af5, bv1, acc[5][1], 0, 0, 0);
    acc[5][2] = __builtin_amdgcn_mfma_f32_16x16x32_bf16(af5, bv2, acc[5][2], 0, 0, 0);
    acc[5][3] = __builtin_amdgcn_mfma_f32_16x16x32_bf16(af5, bv3, acc[5][3], 0, 0, 0);
    __builtin_amdgcn_s_setprio(0);
  }

  // epilogue
  #pragma unroll
  for (int mf = 0; mf < 6; ++mf) {
    int ob = wm*96 + mf*16 + l4*4;     // output channel base (4 consecutive)
    #pragma unroll
    for (int nf = 0; nf < 4; ++nf) {
      int pl = wn*64 + nf*16 + l15;
      int p  = p0 + pl;
      f32x4 v = acc[mf][nf];
      if (MODE == 0) {
        int h = p >> 7, w = p & 127;
        bf16x4 pk;
        #pragma unroll
        for (int jj = 0; jj < 4; ++jj) {
          float xv = v[jj] + bias_lds[ob + jj];
          pk[jj] = (bf16)silu_f(xv);
        }
        size_t basep = (((size_t)b*24 + (ob >> 3))*HP + (h + 1))*HP + (w + 1);
        *(bf16x4*)(outpack + basep*8 + (ob & 7)) = pk;
      } else {
        #pragma unroll
        for (int jj = 0; jj < 4; ++jj) {
          float xv = silu_f(v[jj] + bias_lds[ob + jj]);
          size_t idx = ((size_t)b*CO + ob + jj)*NPX + p;
          outp[idx] = xv + xin[idx];
        }
      }
    }
  }
}

extern "C" void kernel_launch(void* const* d_in, const int* in_sizes, int n_in,
                              void* d_out, int out_size, void* d_ws, size_t ws_size,
                              hipStream_t stream) {
  const float* x        = (const float*)d_in[0];
  const float* latent   = (const float*)d_in[1];
  const float* expert_w = (const float*)d_in[2];
  const float* expert_b = (const float*)d_in[3];
  const float* attn_w   = (const float*)d_in[4];
  const float* attn_b   = (const float*)d_in[5];
  const float* conv2_w  = (const float*)d_in[6];
  const float* conv2_b  = (const float*)d_in[7];
  float* outp = (float*)d_out;

  char* base = (char*)d_ws;
  size_t off = 0;
  float* attn = (float*)(base + off); off += 4096;
  float* bdyn = (float*)(base + off); off += 16384;
  bf16* w_re  = (bf16*)(base + off);  off += (size_t)B_*CO*KTOT*2;      // 10.6 MB
  bf16* w2_re = (bf16*)(base + off);  off += (size_t)CO*KTOT*2;         // 0.66 MB
  bf16* xpack = (bf16*)(base + off);  off += (size_t)B_*24*HPHP*8*2;    // 103.8 MB
  bf16* midpack = (bf16*)(base + off); off += (size_t)B_*24*HPHP*8*2;   // 103.8 MB
  (void)ws_size; (void)in_sizes; (void)n_in; (void)out_size;

  k_attn<<<dim3(1), dim3(128), 0, stream>>>(latent, attn_w, attn_b, attn);
  k_bdyn<<<dim3(12), dim3(256), 0, stream>>>(attn, expert_b, bdyn);
  k_wdyn<<<dim3(CO), dim3(256), 0, stream>>>(expert_w, attn, w_re);
  k_w2re<<<dim3(CO), dim3(256), 0, stream>>>(conv2_w, w2_re);
  k_xpack<<<dim3(130, 24, 16), dim3(128), 0, stream>>>(x, xpack);
  k_midborder<<<dim3(B_*24), dim3(256), 0, stream>>>(midpack);
  k_conv<0><<<dim3(1024), dim3(512), 0, stream>>>(w_re, xpack, bdyn, x, midpack, outp);
  k_conv<1><<<dim3(1024), dim3(512), 0, stream>>>(w2_re, midpack, conv2_b, x, midpack, outp);
}

// Round 4
// 517.714 us; speedup vs baseline: 1.4347x; 1.2524x over previous
//
#include <hip/hip_runtime.h>
#include <stdint.h>

typedef __bf16 bf16;
typedef bf16 bf16x8 __attribute__((ext_vector_type(8)));
typedef bf16 bf16x4 __attribute__((ext_vector_type(4)));
typedef float f32x4 __attribute__((ext_vector_type(4)));

#define B_   16
#define CI   192
#define CO   192
#define H_   128
#define W_   128
#define KE   8
#define LD   64
#define KTOT 1728   // 9*192
#define HP   130    // padded H/W
#define HPHP (HP*HP)
#define NPX  (H_*W_)
#define NT   54     // K-steps of 32

__device__ __forceinline__ void gll16(const void* g, void* l) {
  __builtin_amdgcn_global_load_lds(
      (const __attribute__((address_space(1))) unsigned int*)g,
      (__attribute__((address_space(3))) unsigned int*)l, 16, 0, 0);
}

__device__ __forceinline__ float silu_f(float x) {
  return x / (1.f + __expf(-x));
}

// ---------------- attention softmax: latent[16,64] -> attn[16,8] ----------------
__global__ void k_attn(const float* __restrict__ latent, const float* __restrict__ attn_w,
                       const float* __restrict__ attn_b, float* __restrict__ attn) {
  int t = threadIdx.x;           // 128 threads: b = t>>3, k = t&7
  int b = t >> 3, k = t & 7;
  float s = attn_b[k];
  for (int d = 0; d < LD; ++d) s += latent[b*LD + d] * attn_w[k*LD + d];
  float m = s;
  for (int off = 4; off; off >>= 1) m = fmaxf(m, __shfl_xor(m, off, 8));
  float e = __expf(s - m);
  float sum = e;
  for (int off = 4; off; off >>= 1) sum += __shfl_xor(sum, off, 8);
  attn[t] = e / sum;
}

// ---------------- dynamic bias ----------------
__global__ void k_bdyn(const float* __restrict__ attn, const float* __restrict__ expert_b,
                       float* __restrict__ bdyn) {
  int j = blockIdx.x * 256 + threadIdx.x;
  if (j >= B_ * CO) return;
  int b = j / CO, o = j - b * CO;
  float s = 0.f;
  #pragma unroll
  for (int e = 0; e < KE; ++e) s += attn[b*KE + e] * expert_b[e*CO + o];
  bdyn[j] = s;
}

// ---------------- dynamic weights -> staged layout [b][kt=54][chunk=12][slot=64][8] bf16
__global__ void k_wdyn(const float* __restrict__ expert_w, const float* __restrict__ attn,
                       bf16* __restrict__ w_re) {
  int o = blockIdx.x;            // 192
  int chunk = o >> 4, row = o & 15, c = (row >> 1) & 3;
  __shared__ float ew[KE][KTOT];
  __shared__ float al[B_][KE];
  for (int e = 0; e < KE; ++e)
    for (int j = threadIdx.x; j < KTOT; j += 256)
      ew[e][j] = expert_w[((size_t)e*CO + o)*KTOT + j];   // [i*9+rs]
  if (threadIdx.x < B_*KE) al[threadIdx.x >> 3][threadIdx.x & 7] = attn[threadIdx.x];
  __syncthreads();
  for (int idx = threadIdx.x; idx < B_*KTOT; idx += 256) {
    int b = idx / KTOT, k = idx - b*KTOT;
    int rs = k / 192, i = k - rs*192;
    float s = 0.f;
    #pragma unroll
    for (int e = 0; e < KE; ++e) s += al[b][e] * ew[e][i*9 + rs];
    int kt = k >> 5, kslot = (k >> 3) & 3, j = k & 7;
    int slot = row*4 + (kslot ^ c);
    w_re[((((size_t)b*NT + kt)*12 + chunk)*64 + slot)*8 + j] = (bf16)s;
  }
}

// ---------------- static conv2 weights -> same staged layout (no b) ----------------
__global__ void k_w2re(const float* __restrict__ conv2_w, bf16* __restrict__ w2_re) {
  int o = blockIdx.x;
  int chunk = o >> 4, row = o & 15, c = (row >> 1) & 3;
  __shared__ float cw[KTOT];
  for (int j = threadIdx.x; j < KTOT; j += 256) cw[j] = conv2_w[(size_t)o*KTOT + j];
  __syncthreads();
  for (int k = threadIdx.x; k < KTOT; k += 256) {
    int rs = k / 192, i = k - rs*192;
    int kt = k >> 5, kslot = (k >> 3) & 3, j = k & 7;
    int slot = row*4 + (kslot ^ c);
    w2_re[(((size_t)kt*12 + chunk)*64 + slot)*8 + j] = (bf16)cw[i*9 + rs];
  }
}

// ---------------- pack+pad x: f32 NCHW -> bf16 [b][i/8][130][130][8], zero borders ----------------
__global__ void k_xpack(const float* __restrict__ x, bf16* __restrict__ xpack) {
  int h2 = blockIdx.x, ib = blockIdx.y, b = blockIdx.z;
  size_t rowbase = (((size_t)b*24 + ib)*HP + h2)*HP;
  int t = threadIdx.x;  // 128
  if (h2 == 0 || h2 == HP-1) {
    uint4 z = make_uint4(0,0,0,0);
    for (int w = t; w < HP; w += 128) *(uint4*)(xpack + (rowbase + w)*8) = z;
    return;
  }
  __shared__ float tt[8][128];
  int h = h2 - 1;
  #pragma unroll
  for (int ii = 0; ii < 8; ++ii)
    tt[ii][t] = x[(((size_t)b*CI + ib*8 + ii)*H_ + h)*W_ + t];
  __syncthreads();
  bf16x8 v;
  #pragma unroll
  for (int ii = 0; ii < 8; ++ii) v[ii] = (bf16)tt[ii][t];
  *(bf16x8*)(xpack + (rowbase + t + 1)*8) = v;
  if (t == 0) {
    uint4 z = make_uint4(0,0,0,0);
    *(uint4*)(xpack + rowbase*8) = z;
    *(uint4*)(xpack + (rowbase + HP-1)*8) = z;
  }
}

// ---------------- zero borders of midpack ----------------
__global__ void k_midborder(bf16* __restrict__ midpack) {
  int bi = blockIdx.x;  // b*24+ib
  size_t base = (size_t)bi * HPHP;
  uint4 z = make_uint4(0,0,0,0);
  for (int j = threadIdx.x; j < 516; j += 256) {
    int h2, w2;
    if (j < 130)      { h2 = 0;       w2 = j; }
    else if (j < 260) { h2 = 129;     w2 = j - 130; }
    else if (j < 388) { h2 = j - 259; w2 = 0; }
    else              { h2 = j - 387; w2 = 129; }
    *(uint4*)(midpack + (base + (size_t)h2*HP + w2)*8) = z;
  }
}

// ---------------- implicit-GEMM 3x3 conv, BM=192 x BN=256(2 rows) x BK=32 ----------------
// 4 waves (2m x 2n), per-wave 96x128. Deep pipeline:
//   A double-buffered (depth 1: L2-resident weights), B triple-buffered (depth 2: HBM-safe).
//   Per step: entry s_waitcnt vmcnt(4) [keep B(t+2) in flight] + one s_barrier;
//   ds_read af[6] + stream bv[8]; issue A(t+1) 3x gll16 + B(t+2) 4x gll16; 48 MFMA.
template<int MODE>
__global__ __launch_bounds__(256, 2)
void k_conv(const bf16* __restrict__ wre, const bf16* __restrict__ inpack,
            const float* __restrict__ bias_g, const float* __restrict__ xin,
            bf16* __restrict__ outpack, float* __restrict__ outp) {
  const int tid  = threadIdx.x;
  const int lane = tid & 63;
  const int wv   = tid >> 6;          // 0..3
  const int wm   = wv >> 1;           // 0..1 (o half)
  const int wn   = wv & 1;            // 0..1 (p half)
  const int l15  = lane & 15, l4 = lane >> 4;

  // XCD-aware chunked remap: 1024 blocks, 128/XCD => each XCD owns 2 batches
  const int bid  = blockIdx.x;
  const int n    = (bid & 7) * 128 + (bid >> 3);
  const int b    = n >> 6;
  const int tile = n & 63;
  const int p0   = tile * 256;
  const int h0   = tile * 2;

  __shared__ __align__(16) bf16 Alds[2][12*512];   // 24 KB
  __shared__ __align__(16) bf16 Blds[3][16*512];   // 48 KB
  __shared__ float bias_lds[CO];

  if (tid < CO) bias_lds[tid] = (MODE == 0) ? bias_g[b*CO + tid] : bias_g[tid];

  const size_t wbase = (MODE == 0) ? ((size_t)b*CO*KTOT) : 0;

  // ---- staging pointers ----
  // A: chunks {wv, wv+4, wv+8}; src chunk c at +c*4*512 elements; +6144/step
  const bf16* aS = wre + wbase + (size_t)wv*512 + lane*8;
  // B: wave wv stages channel-group kg=wv for 4 px-chunks c=0..3
  //    px p = c*64+lane -> row (c>>1), col (c&1)*64+lane
  const bf16* bS[4];
  #pragma unroll
  for (int c = 0; c < 4; ++c)
    bS[c] = inpack + ((((size_t)b*24 + wv)*HP + h0 + (c >> 1))*HP + (c & 1)*64 + lane)*8;

  int rsn = 0, ibn = 0, boff = 0;
  auto badv = [&]() {
    if (++ibn == 6) {
      ibn = 0; ++rsn;
      boff += (((rsn % 3) == 0) ? (HP - 2) : 1) * 8 - 20*HPHP*8;
    } else {
      boff += 4*HPHP*8;
    }
  };

  f32x4 acc[6][8];
  #pragma unroll
  for (int mf = 0; mf < 6; ++mf)
    #pragma unroll
    for (int nf = 0; nf < 8; ++nf)
      #pragma unroll
      for (int jj = 0; jj < 4; ++jj) acc[mf][nf][jj] = 0.f;

  const int sw = l15*4 + (l4 ^ ((l15 >> 1) & 3));   // swizzled A slot (2-way, free)

  // ---- prologue: A(0) -> Abuf0, B(0) -> Bbuf0, B(1) -> Bbuf1 ----
  {
    #pragma unroll
    for (int c = 0; c < 3; ++c) gll16(aS + c*2048, &Alds[0][(wv + c*4)*512]);
    aS += 6144;
    #pragma unroll
    for (int c = 0; c < 4; ++c) gll16(bS[c] + boff, &Blds[0][(wv*4 + c)*512]);
    badv();
    #pragma unroll
    for (int c = 0; c < 4; ++c) gll16(bS[c] + boff, &Blds[1][(wv*4 + c)*512]);
    badv();
  }

  int bcur = 0, bnxt = 2;
  for (int t = 0; t < NT; ++t) {
    // entry: buffer t ready for THIS wave; barrier joins all waves' staging
    if (t < NT-1) asm volatile("s_waitcnt vmcnt(4)" ::: "memory");
    else          asm volatile("s_waitcnt vmcnt(0)" ::: "memory");
    asm volatile("s_barrier" ::: "memory");

    const bf16* A  = Alds[t & 1];
    const bf16* Bp = Blds[bcur];

    bf16x8 af0 = *(const bf16x8*)(A + (wm*6 + 0)*512 + sw*8);
    bf16x8 af1 = *(const bf16x8*)(A + (wm*6 + 1)*512 + sw*8);
    bf16x8 af2 = *(const bf16x8*)(A + (wm*6 + 2)*512 + sw*8);
    bf16x8 af3 = *(const bf16x8*)(A + (wm*6 + 3)*512 + sw*8);
    bf16x8 af4 = *(const bf16x8*)(A + (wm*6 + 4)*512 + sw*8);
    bf16x8 af5 = *(const bf16x8*)(A + (wm*6 + 5)*512 + sw*8);

    if (t + 1 < NT) {
      bf16* An = (bf16*)Alds[(t+1) & 1];
      #pragma unroll
      for (int c = 0; c < 3; ++c) gll16(aS + c*2048, An + (wv + c*4)*512);
      aS += 6144;
    }
    if (t + 2 < NT) {
      bf16* Bn = (bf16*)Blds[bnxt];
      #pragma unroll
      for (int c = 0; c < 4; ++c) gll16(bS[c] + boff, Bn + (wv*4 + c)*512);
      badv();
    }

    __builtin_amdgcn_s_setprio(1);
    #pragma unroll
    for (int nf = 0; nf < 8; ++nf) {
      bf16x8 bv = *(const bf16x8*)(Bp + (size_t)(l4*256 + wn*128 + nf*16 + l15)*8);
      acc[0][nf] = __builtin_amdgcn_mfma_f32_16x16x32_bf16(af0, bv, acc[0][nf], 0, 0, 0);
      acc[1][nf] = __builtin_amdgcn_mfma_f32_16x16x32_bf16(af1, bv, acc[1][nf], 0, 0, 0);
      acc[2][nf] = __builtin_amdgcn_mfma_f32_16x16x32_bf16(af2, bv, acc[2][nf], 0, 0, 0);
      acc[3][nf] = __builtin_amdgcn_mfma_f32_16x16x32_bf16(af3, bv, acc[3][nf], 0, 0, 0);
      acc[4][nf] = __builtin_amdgcn_mfma_f32_16x16x32_bf16(af4, bv, acc[4][nf], 0, 0, 0);
      acc[5][nf] = __builtin_amdgcn_mfma_f32_16x16x32_bf16(af5, bv, acc[5][nf], 0, 0, 0);
    }
    __builtin_amdgcn_s_setprio(0);

    bcur = (bcur == 2) ? 0 : bcur + 1;
    bnxt = (bnxt == 2) ? 0 : bnxt + 1;
  }

  // epilogue
  #pragma unroll
  for (int mf = 0; mf < 6; ++mf) {
    int ob = wm*96 + mf*16 + l4*4;     // output channel base (4 consecutive)
    #pragma unroll
    for (int nf = 0; nf < 8; ++nf) {
      int pl = wn*128 + nf*16 + l15;
      int p  = p0 + pl;
      f32x4 v = acc[mf][nf];
      if (MODE == 0) {
        int h = p >> 7, w = p & 127;
        bf16x4 pk;
        #pragma unroll
        for (int jj = 0; jj < 4; ++jj) {
          float xv = v[jj] + bias_lds[ob + jj];
          pk[jj] = (bf16)silu_f(xv);
        }
        size_t basep = (((size_t)b*24 + (ob >> 3))*HP + (h + 1))*HP + (w + 1);
        *(bf16x4*)(outpack + basep*8 + (ob & 7)) = pk;
      } else {
        #pragma unroll
        for (int jj = 0; jj < 4; ++jj) {
          float xv = silu_f(v[jj] + bias_lds[ob + jj]);
          size_t idx = ((size_t)b*CO + ob + jj)*NPX + p;
          outp[idx] = xv + xin[idx];
        }
      }
    }
  }
}

extern "C" void kernel_launch(void* const* d_in, const int* in_sizes, int n_in,
                              void* d_out, int out_size, void* d_ws, size_t ws_size,
                              hipStream_t stream) {
  const float* x        = (const float*)d_in[0];
  const float* latent   = (const float*)d_in[1];
  const float* expert_w = (const float*)d_in[2];
  const float* expert_b = (const float*)d_in[3];
  const float* attn_w   = (const float*)d_in[4];
  const float* attn_b   = (const float*)d_in[5];
  const float* conv2_w  = (const float*)d_in[6];
  const float* conv2_b  = (const float*)d_in[7];
  float* outp = (float*)d_out;

  char* base = (char*)d_ws;
  size_t off = 0;
  float* attn = (float*)(base + off); off += 4096;
  float* bdyn = (float*)(base + off); off += 16384;
  bf16* w_re  = (bf16*)(base + off);  off += (size_t)B_*CO*KTOT*2;      // 10.6 MB
  bf16* w2_re = (bf16*)(base + off);  off += (size_t)CO*KTOT*2;         // 0.66 MB
  bf16* xpack = (bf16*)(base + off);  off += (size_t)B_*24*HPHP*8*2;    // 103.8 MB
  bf16* midpack = (bf16*)(base + off); off += (size_t)B_*24*HPHP*8*2;   // 103.8 MB
  (void)ws_size; (void)in_sizes; (void)n_in; (void)out_size;

  k_attn<<<dim3(1), dim3(128), 0, stream>>>(latent, attn_w, attn_b, attn);
  k_bdyn<<<dim3(12), dim3(256), 0, stream>>>(attn, expert_b, bdyn);
  k_wdyn<<<dim3(CO), dim3(256), 0, stream>>>(expert_w, attn, w_re);
  k_w2re<<<dim3(CO), dim3(256), 0, stream>>>(conv2_w, w2_re);
  k_xpack<<<dim3(130, 24, 16), dim3(128), 0, stream>>>(x, xpack);
  k_midborder<<<dim3(B_*24), dim3(256), 0, stream>>>(midpack);
  k_conv<0><<<dim3(1024), dim3(256), 0, stream>>>(w_re, xpack, bdyn, x, midpack, outp);
  k_conv<1><<<dim3(1024), dim3(256), 0, stream>>>(w2_re, midpack, conv2_b, x, midpack, outp);
}

// Round 5
// 501.401 us; speedup vs baseline: 1.4814x; 1.0325x over previous
//
#include <hip/hip_runtime.h>
#include <stdint.h>
#include <stddef.h>

typedef __bf16 bf16;
typedef bf16 bf16x8 __attribute__((ext_vector_type(8)));
typedef bf16 bf16x4 __attribute__((ext_vector_type(4)));
typedef float f32x4 __attribute__((ext_vector_type(4)));

#define B_   16
#define CI   192
#define CO   192
#define H_   128
#define W_   128
#define KE   8
#define LD   64
#define KTOT 1728   // 9*192
#define HP   130    // padded H/W
#define HPHP (HP*HP)
#define NPX  (H_*W_)
#define NT   54     // K micro-steps of 32 (order: r-major, ib, s-minor)

__device__ __forceinline__ void gll16(const void* g, void* l) {
  __builtin_amdgcn_global_load_lds(
      (const __attribute__((address_space(1))) unsigned int*)g,
      (__attribute__((address_space(3))) unsigned int*)l, 16, 0, 0);
}

__device__ __forceinline__ float silu_f(float x) {
  return x / (1.f + __expf(-x));
}

// ---------------- attention softmax: latent[16,64] -> attn[16,8] ----------------
__global__ void k_attn(const float* __restrict__ latent, const float* __restrict__ attn_w,
                       const float* __restrict__ attn_b, float* __restrict__ attn) {
  int t = threadIdx.x;           // 128 threads: b = t>>3, k = t&7
  int b = t >> 3, k = t & 7;
  float s = attn_b[k];
  for (int d = 0; d < LD; ++d) s += latent[b*LD + d] * attn_w[k*LD + d];
  float m = s;
  for (int off = 4; off; off >>= 1) m = fmaxf(m, __shfl_xor(m, off, 8));
  float e = __expf(s - m);
  float sum = e;
  for (int off = 4; off; off >>= 1) sum += __shfl_xor(sum, off, 8);
  attn[t] = e / sum;
}

// ---------------- dynamic bias ----------------
__global__ void k_bdyn(const float* __restrict__ attn, const float* __restrict__ expert_b,
                       float* __restrict__ bdyn) {
  int j = blockIdx.x * 256 + threadIdx.x;
  if (j >= B_ * CO) return;
  int b = j / CO, o = j - b * CO;
  float s = 0.f;
  #pragma unroll
  for (int e = 0; e < KE; ++e) s += attn[b*KE + e] * expert_b[e*CO + o];
  bdyn[j] = s;
}

// ---------------- dynamic weights -> staged layout [b][kt=54][chunk=12][slot=64][8] bf16
// K order: kt = r*18 + ib*3 + s  (s innermost). slot L holds (row=L>>2, ks=(L&3)^((row>>1)&3)).
// element: o = chunk*16+row, i = ib*32 + ks*8 + j, weight (o, i, r, s).
__global__ void k_wdyn(const float* __restrict__ expert_w, const float* __restrict__ attn,
                       bf16* __restrict__ w_re) {
  int o = blockIdx.x;            // 192
  int chunk = o >> 4, row = o & 15, c = (row >> 1) & 3;
  __shared__ float ew[KE][KTOT];
  __shared__ float al[B_][KE];
  for (int e = 0; e < KE; ++e)
    for (int j = threadIdx.x; j < KTOT; j += 256)
      ew[e][j] = expert_w[((size_t)e*CO + o)*KTOT + j];   // [i*9+rs]
  if (threadIdx.x < B_*KE) al[threadIdx.x >> 3][threadIdx.x & 7] = attn[threadIdx.x];
  __syncthreads();
  for (int idx = threadIdx.x; idx < B_*KTOT; idx += 256) {
    int b = idx / KTOT, k = idx - b*KTOT;
    int kt = k >> 5, ks = (k >> 3) & 3, j = k & 7;
    int r = kt / 18, t2 = kt - r*18;
    int ibb = t2 / 3, s = t2 - ibb*3;
    int i = ibb*32 + ks*8 + j;
    float acc = 0.f;
    #pragma unroll
    for (int e = 0; e < KE; ++e) acc += al[b][e] * ew[e][i*9 + r*3 + s];
    int slot = row*4 + (ks ^ c);
    w_re[((((size_t)b*NT + kt)*12 + chunk)*64 + slot)*8 + j] = (bf16)acc;
  }
}

// ---------------- static conv2 weights -> same staged layout (no b) ----------------
__global__ void k_w2re(const float* __restrict__ conv2_w, bf16* __restrict__ w2_re) {
  int o = blockIdx.x;
  int chunk = o >> 4, row = o & 15, c = (row >> 1) & 3;
  __shared__ float cw[KTOT];
  for (int j = threadIdx.x; j < KTOT; j += 256) cw[j] = conv2_w[(size_t)o*KTOT + j];
  __syncthreads();
  for (int k = threadIdx.x; k < KTOT; k += 256) {
    int kt = k >> 5, ks = (k >> 3) & 3, j = k & 7;
    int r = kt / 18, t2 = kt - r*18;
    int ibb = t2 / 3, s = t2 - ibb*3;
    int i = ibb*32 + ks*8 + j;
    int slot = row*4 + (ks ^ c);
    w2_re[(((size_t)kt*12 + chunk)*64 + slot)*8 + j] = (bf16)cw[i*9 + r*3 + s];
  }
}

// ---------------- pack+pad x: f32 NCHW -> bf16 [b][i/8][130][130][8], zero borders ----------------
__global__ void k_xpack(const float* __restrict__ x, bf16* __restrict__ xpack) {
  int h2 = blockIdx.x, ib = blockIdx.y, b = blockIdx.z;
  size_t rowbase = (((size_t)b*24 + ib)*HP + h2)*HP;
  int t = threadIdx.x;  // 128
  if (h2 == 0 || h2 == HP-1) {
    uint4 z = make_uint4(0,0,0,0);
    for (int w = t; w < HP; w += 128) *(uint4*)(xpack + (rowbase + w)*8) = z;
    return;
  }
  __shared__ float tt[8][128];
  int h = h2 - 1;
  #pragma unroll
  for (int ii = 0; ii < 8; ++ii)
    tt[ii][t] = x[(((size_t)b*CI + ib*8 + ii)*H_ + h)*W_ + t];
  __syncthreads();
  bf16x8 v;
  #pragma unroll
  for (int ii = 0; ii < 8; ++ii) v[ii] = (bf16)tt[ii][t];
  *(bf16x8*)(xpack + (rowbase + t + 1)*8) = v;
  if (t == 0) {
    uint4 z = make_uint4(0,0,0,0);
    *(uint4*)(xpack + rowbase*8) = z;
    *(uint4*)(xpack + (rowbase + HP-1)*8) = z;
  }
}

// ---------------- zero borders of midpack ----------------
__global__ void k_midborder(bf16* __restrict__ midpack) {
  int bi = blockIdx.x;  // b*24+ib
  size_t base = (size_t)bi * HPHP;
  uint4 z = make_uint4(0,0,0,0);
  for (int j = threadIdx.x; j < 516; j += 256) {
    int h2, w2;
    if (j < 130)      { h2 = 0;       w2 = j; }
    else if (j < 260) { h2 = 129;     w2 = j - 130; }
    else if (j < 388) { h2 = j - 259; w2 = 0; }
    else              { h2 = j - 387; w2 = 129; }
    *(uint4*)(midpack + (base + (size_t)h2*HP + w2)*8) = z;
  }
}

// ---------------- implicit-GEMM 3x3 conv, BM=192 x BN=256(2 rows), K order (r,ib,s) ----------------
// 4 waves (2m x 2n), per-wave 96x128. 54 micro-steps = 18 macros (r,ib) x 3 micros (s).
// B staged once per macro (4 kg x 2 rows x 130 cols, 5 overlapped 1KB chunks/kg); s served
// by +16B shift on the LDS read. A triple-buffered (lead 2 micros, buf idx = s statically),
// B double-buffered (lead 3 micros). Entry waits: vmcnt(3)/s0, (3)/s1, (8)/s2, 0 at tail.
template<int MODE>
__global__ __launch_bounds__(256, 2)
void k_conv(const bf16* __restrict__ wre, const bf16* __restrict__ inpack,
            const float* __restrict__ bias_g, const bf16* __restrict__ respack,
            bf16* __restrict__ outpack, float* __restrict__ outp) {
  const int tid  = threadIdx.x;
  const int lane = tid & 63;
  const int wv   = tid >> 6;          // 0..3
  const int wm   = wv >> 1;           // 0..1 (o half)
  const int wn   = wv & 1;            // 0..1 (p half = image row)
  const int l15  = lane & 15, l4 = lane >> 4;

  // XCD-aware chunked remap: 1024 blocks, 128/XCD => each XCD owns 2 batches
  const int bid  = blockIdx.x;
  const int n    = (bid & 7) * 128 + (bid >> 3);
  const int b    = n >> 6;
  const int tile = n & 63;
  const int p0   = tile * 256;
  const int h0   = tile * 2;

  __shared__ __align__(16) bf16 Alds[3][12*512];    // 36864 B
  __shared__ __align__(16) bf16 Blds[2][4*2560];    // 40960 B
  __shared__ float bias_lds[CO];

  if (tid < CO) bias_lds[tid] = (MODE == 0) ? bias_g[b*CO + tid] : bias_g[tid];

  const size_t wbase = (MODE == 0) ? ((size_t)b*CO*KTOT) : 0;

  // A staging: 12 chunks of 1KB per micro-step; wave wv stages {wv, wv+4, wv+8}
  const bf16* aS = wre + wbase + (size_t)wv*512 + lane*8;
  // B staging: wave wv stages kg=wv; 5 overlapped chunks over contiguous row-pair (4160B)
  const bf16* bbase = inpack + (((size_t)b*24 + wv)*HPHP + (size_t)h0*HP)*8 + lane*8;
  int ibm = 0; ptrdiff_t boffEl = 0;   // macro (r,ib) element offset

  auto stageA = [&](bf16* dbuf) {
    bf16* d = dbuf + wv*512;
    gll16(aS,        d);
    gll16(aS + 2048, d + 2048);
    gll16(aS + 4096, d + 4096);
    aS += 6144;
  };
  auto stageB = [&](bf16* dbuf) {
    const bf16* src = bbase + boffEl;
    bf16* d = dbuf + wv*2560;
    gll16(src,        d);
    gll16(src +  512, d +  512);
    gll16(src + 1024, d + 1024);
    gll16(src + 1536, d + 1536);
    gll16(src + 1568, d + 1568);   // overlapped tail chunk (3136..4159 B)
    if (++ibm == 6) { ibm = 0; boffEl += (ptrdiff_t)(HP - 20*HPHP)*8; }
    else boffEl += (ptrdiff_t)4*HPHP*8;
  };

  f32x4 acc[6][8];
  #pragma unroll
  for (int mf = 0; mf < 6; ++mf)
    #pragma unroll
    for (int nf = 0; nf < 8; ++nf)
      #pragma unroll
      for (int jj = 0; jj < 4; ++jj) acc[mf][nf][jj] = 0.f;

  const int sw = l15*4 + (l4 ^ ((l15 >> 1) & 3));       // swizzled A slot
  const int bvb = l4*2560 + (wn*130 + l15)*8;           // B read base (elements)

  // prologue: A(0), A(1), B(0)
  stageA(Alds[0]);
  stageA(Alds[1]);
  stageB(Blds[0]);

  bf16* Bcur = (bf16*)Blds[0];
  bf16* Bnxt = (bf16*)Blds[1];

  for (int m = 0; m < 18; ++m) {
    #pragma unroll
    for (int s = 0; s < 3; ++s) {
      // ---- entry wait + barrier ----
      if (s == 2) {
        if (m == 17) asm volatile("s_waitcnt vmcnt(0)" ::: "memory");
        else         asm volatile("s_waitcnt vmcnt(8)" ::: "memory");
      } else {
        asm volatile("s_waitcnt vmcnt(3)" ::: "memory");
      }
      asm volatile("s_barrier" ::: "memory");

      const bf16* A = Alds[s];          // u%3 == s
      bf16x8 af0 = *(const bf16x8*)(A + (wm*6 + 0)*512 + sw*8);
      bf16x8 af1 = *(const bf16x8*)(A + (wm*6 + 1)*512 + sw*8);
      bf16x8 af2 = *(const bf16x8*)(A + (wm*6 + 2)*512 + sw*8);
      bf16x8 af3 = *(const bf16x8*)(A + (wm*6 + 3)*512 + sw*8);
      bf16x8 af4 = *(const bf16x8*)(A + (wm*6 + 4)*512 + sw*8);
      bf16x8 af5 = *(const bf16x8*)(A + (wm*6 + 5)*512 + sw*8);

      if (3*m + s + 2 < NT) stageA(Alds[(s+2)%3]);     // A(u+2)
      if (s == 1 && m < 17) stageB(Bnxt);              // B(m+1)

      const bf16* bp = Bcur + bvb + s*8;
      __builtin_amdgcn_s_setprio(1);
      #pragma unroll
      for (int nf = 0; nf < 8; ++nf) {
        bf16x8 bv = *(const bf16x8*)(bp + nf*128);
        acc[0][nf] = __builtin_amdgcn_mfma_f32_16x16x32_bf16(af0, bv, acc[0][nf], 0, 0, 0);
        acc[1][nf] = __builtin_amdgcn_mfma_f32_16x16x32_bf16(af1, bv, acc[1][nf], 0, 0, 0);
        acc[2][nf] = __builtin_amdgcn_mfma_f32_16x16x32_bf16(af2, bv, acc[2][nf], 0, 0, 0);
        acc[3][nf] = __builtin_amdgcn_mfma_f32_16x16x32_bf16(af3, bv, acc[3][nf], 0, 0, 0);
        acc[4][nf] = __builtin_amdgcn_mfma_f32_16x16x32_bf16(af4, bv, acc[4][nf], 0, 0, 0);
        acc[5][nf] = __builtin_amdgcn_mfma_f32_16x16x32_bf16(af5, bv, acc[5][nf], 0, 0, 0);
      }
      __builtin_amdgcn_s_setprio(0);
    }
    { bf16* t = Bcur; Bcur = Bnxt; Bnxt = t; }
  }

  // epilogue
  #pragma unroll
  for (int mf = 0; mf < 6; ++mf) {
    int ob = wm*96 + mf*16 + l4*4;     // output channel base (4 consecutive)
    #pragma unroll
    for (int nf = 0; nf < 8; ++nf) {
      int pl = wn*128 + nf*16 + l15;
      int p  = p0 + pl;
      f32x4 v = acc[mf][nf];
      int h = p >> 7, w = p & 127;
      size_t basep = (((size_t)b*24 + (ob >> 3))*HP + (h + 1))*HP + (w + 1);
      if (MODE == 0) {
        bf16x4 pk;
        #pragma unroll
        for (int jj = 0; jj < 4; ++jj) {
          float xv = v[jj] + bias_lds[ob + jj];
          pk[jj] = (bf16)silu_f(xv);
        }
        *(bf16x4*)(outpack + basep*8 + (ob & 7)) = pk;
      } else {
        bf16x4 rr = *(const bf16x4*)(respack + basep*8 + (ob & 7));
        #pragma unroll
        for (int jj = 0; jj < 4; ++jj) {
          float xv = silu_f(v[jj] + bias_lds[ob + jj]);
          size_t idx = ((size_t)b*CO + ob + jj)*NPX + p;
          outp[idx] = xv + (float)rr[jj];
        }
      }
    }
  }
}

extern "C" void kernel_launch(void* const* d_in, const int* in_sizes, int n_in,
                              void* d_out, int out_size, void* d_ws, size_t ws_size,
                              hipStream_t stream) {
  const float* x        = (const float*)d_in[0];
  const float* latent   = (const float*)d_in[1];
  const float* expert_w = (const float*)d_in[2];
  const float* expert_b = (const float*)d_in[3];
  const float* attn_w   = (const float*)d_in[4];
  const float* attn_b   = (const float*)d_in[5];
  const float* conv2_w  = (const float*)d_in[6];
  const float* conv2_b  = (const float*)d_in[7];
  float* outp = (float*)d_out;

  char* base = (char*)d_ws;
  size_t off = 0;
  float* attn = (float*)(base + off); off += 4096;
  float* bdyn = (float*)(base + off); off += 16384;
  bf16* w_re  = (bf16*)(base + off);  off += (size_t)B_*CO*KTOT*2;      // 10.6 MB
  bf16* w2_re = (bf16*)(base + off);  off += (size_t)CO*KTOT*2;         // 0.66 MB
  bf16* xpack = (bf16*)(base + off);  off += (size_t)B_*24*HPHP*8*2;    // 103.8 MB
  bf16* midpack = (bf16*)(base + off); off += (size_t)B_*24*HPHP*8*2;   // 103.8 MB
  (void)ws_size; (void)in_sizes; (void)n_in; (void)out_size;

  k_attn<<<dim3(1), dim3(128), 0, stream>>>(latent, attn_w, attn_b, attn);
  k_bdyn<<<dim3(12), dim3(256), 0, stream>>>(attn, expert_b, bdyn);
  k_wdyn<<<dim3(CO), dim3(256), 0, stream>>>(expert_w, attn, w_re);
  k_w2re<<<dim3(CO), dim3(256), 0, stream>>>(conv2_w, w2_re);
  k_xpack<<<dim3(130, 24, 16), dim3(128), 0, stream>>>(x, xpack);
  k_midborder<<<dim3(B_*24), dim3(256), 0, stream>>>(midpack);
  k_conv<0><<<dim3(1024), dim3(256), 0, stream>>>(w_re, xpack, bdyn, xpack, midpack, outp);
  k_conv<1><<<dim3(1024), dim3(256), 0, stream>>>(w2_re, midpack, conv2_b, xpack, midpack, outp);
}